// Round 1
// baseline (1684.254 us; speedup 1.0000x reference)
//
#include <hip/hip_runtime.h>
#include <hip/hip_bf16.h>
#include <math.h>

// GatingFunc: logits = x @ W^T + b; top-2 -> softmax -> scatter to [N, E].
// N=131072, D=1024, E=64, K=2 (fp32 in, fp32 out).
//
// Strategy (round 1, correctness + solid fp32 baseline):
//  - 1 thread per token, 64 fp32 accumulators in VGPRs.
//  - x row streamed once as float4 (sequential per thread; lines fully consumed).
//  - W and b indexed only by wave-uniform loop variables -> scalar (s_load) path.
//  - fp32 accumulation keeps logit error ~1e-7 so top-2 selection matches the
//    numpy reference (any index flip would cost ~0.4 absmax; threshold is 0.019).

#define D_MODEL 1024
#define N_EXP   64

__global__ __launch_bounds__(256) void gating_kernel(
    const float* __restrict__ x,
    const float* __restrict__ W,
    const float* __restrict__ b,
    float* __restrict__ out,
    int n_tokens)
{
    const int t = blockIdx.x * blockDim.x + threadIdx.x;
    if (t >= n_tokens) return;

    const float4* __restrict__ x4 = reinterpret_cast<const float4*>(x + (size_t)t * D_MODEL);
    const float4* __restrict__ W4 = reinterpret_cast<const float4*>(W);

    float acc[N_EXP];
#pragma unroll
    for (int e = 0; e < N_EXP; ++e) acc[e] = b[e];   // uniform -> s_load

    // Main GEMV: 256 float4 chunks of the token's row; per chunk, 64 experts x 4 FMAs.
    for (int dc = 0; dc < D_MODEL / 4; ++dc) {
        const float4 xv = x4[dc];
#pragma unroll
        for (int e = 0; e < N_EXP; ++e) {
            const float4 wv = W4[e * (D_MODEL / 4) + dc];  // uniform address -> s_load_dwordx4
            float a = acc[e];
            a = fmaf(xv.x, wv.x, a);
            a = fmaf(xv.y, wv.y, a);
            a = fmaf(xv.z, wv.z, a);
            a = fmaf(xv.w, wv.w, a);
            acc[e] = a;
        }
    }

    // Top-2 (ties: lower index first, matching jax.lax.top_k).
    float m1 = -INFINITY, m2 = -INFINITY;
    int i1 = 0, i2 = 0;
#pragma unroll
    for (int e = 0; e < N_EXP; ++e) {
        const float v = acc[e];
        if (v > m1) { m2 = m1; i2 = i1; m1 = v; i1 = e; }
        else if (v > m2) { m2 = v; i2 = e; }
    }

    // Softmax over the two selected logits (m1 >= m2, numerically safe).
    const float e2 = expf(m2 - m1);
    const float inv = 1.0f / (1.0f + e2);
    const float g1 = inv;
    const float g2 = e2 * inv;

    // Scatter row: zeros except columns i1, i2. float4 stores (16B/lane).
    float4* __restrict__ out4 = reinterpret_cast<float4*>(out + (size_t)t * N_EXP);
#pragma unroll
    for (int c = 0; c < N_EXP / 4; ++c) {
        float4 o;
        const int e0 = c * 4;
        o.x = (e0 + 0 == i1) ? g1 : ((e0 + 0 == i2) ? g2 : 0.0f);
        o.y = (e0 + 1 == i1) ? g1 : ((e0 + 1 == i2) ? g2 : 0.0f);
        o.z = (e0 + 2 == i1) ? g1 : ((e0 + 2 == i2) ? g2 : 0.0f);
        o.w = (e0 + 3 == i1) ? g1 : ((e0 + 3 == i2) ? g2 : 0.0f);
        out4[c] = o;
    }
}

extern "C" void kernel_launch(void* const* d_in, const int* in_sizes, int n_in,
                              void* d_out, int out_size, void* d_ws, size_t ws_size,
                              hipStream_t stream) {
    const float* x = (const float*)d_in[0];
    const float* W = (const float*)d_in[1];
    const float* b = (const float*)d_in[2];
    float* out = (float*)d_out;

    const int n_tokens = in_sizes[0] / D_MODEL;   // 131072
    const int block = 256;
    const int grid = (n_tokens + block - 1) / block;  // 512 blocks

    gating_kernel<<<grid, block, 0, stream>>>(x, W, b, out, n_tokens);
}